// Round 4
// baseline (547.719 us; speedup 1.0000x reference)
//
#include <hip/hip_runtime.h>

#define SEQ 4096
#define DM 1024
#define NH 16
#define HD 64

typedef __attribute__((ext_vector_type(8))) short short8;
typedef __attribute__((ext_vector_type(4))) short short4v;
typedef __attribute__((ext_vector_type(2))) short short2v;
typedef __attribute__((ext_vector_type(4))) float float4v;

__device__ __forceinline__ short f2bf(float f) {
    union { float f; unsigned u; } v; v.f = f;
    unsigned u = v.u;
    return (short)((u + 0x7fffu + ((u >> 16) & 1u)) >> 16);
}
// round-half-up bf16 (cheaper); used for P where tiny bias is irrelevant
__device__ __forceinline__ short f2bf_fast(float f) {
    union { float f; unsigned u; } v; v.f = f;
    return (short)((v.u + 0x8000u) >> 16);
}

__device__ __forceinline__ void gload_lds16(const void* g, void* l) {
    __builtin_amdgcn_global_load_lds(
        (const __attribute__((address_space(1))) void*)g,
        (__attribute__((address_space(3))) void*)l, 16, 0, 0);
}

// ---------------- cast x (fp32 -> bf16), vectorized ----------------
__global__ void cast_x(const float* __restrict__ in, short* __restrict__ out, int n4) {
    int i = blockIdx.x * blockDim.x + threadIdx.x;
    if (i < n4) {
        float4v x = ((const float4v*)in)[i];
        short4v o;
        o[0] = f2bf(x[0]); o[1] = f2bf(x[1]); o[2] = f2bf(x[2]); o[3] = f2bf(x[3]);
        ((short4v*)out)[i] = o;
    }
}

// ------ transpose + cast: fp32 [H][W] -> bf16 [W][H]; rows < scaled_rows get *scale ------
__global__ void transpose_cast(const float* __restrict__ in, short* __restrict__ out,
                               int H, int W, int scaled_rows, float scale) {
    __shared__ float tile[32][33];
    int bx = blockIdx.x * 32, by = blockIdx.y * 32;
    int tx = threadIdx.x, ty = threadIdx.y;   // 32 x 8
#pragma unroll
    for (int i = 0; i < 32; i += 8)
        tile[ty + i][tx] = in[(by + ty + i) * W + bx + tx];
    __syncthreads();
#pragma unroll
    for (int i = 0; i < 32; i += 8) {
        int orow = bx + ty + i;
        float sc = (orow < scaled_rows) ? scale : 1.0f;
        out[orow * H + by + tx] = f2bf(tile[tx][ty + i] * sc);
    }
}

// ------- V transpose: qkv bf16 [l][2048+h*64+d] -> vt [h][d][l], 64x64 short2 tiles -------
__global__ void transpose_v(const short* __restrict__ qkv, short* __restrict__ vt) {
    __shared__ short tile[64][66];
    int h = blockIdx.z;
    int l0 = blockIdx.x * 64;
    int tx = threadIdx.x, ty = threadIdx.y;   // 32 x 8
#pragma unroll
    for (int i = 0; i < 8; i++) {
        int r = ty + i * 8;
        short2v v = *(const short2v*)&qkv[(l0 + r) * (3 * DM) + 2 * DM + h * HD + 2 * tx];
        tile[r][2 * tx] = v[0];
        tile[r][2 * tx + 1] = v[1];
    }
    __syncthreads();
#pragma unroll
    for (int i = 0; i < 8; i++) {
        int d = ty + i * 8;
        short2v v;
        v[0] = tile[2 * tx][d];
        v[1] = tile[2 * tx + 1][d];
        *(short2v*)&vt[(h * HD + d) * SEQ + l0 + 2 * tx] = v;
    }
}

// ------------- GEMM: A[M,K] bf16 x BT[N,K] bf16 -> C[M,N], 128x128 tile -------------
template <typename OutT>
__global__ __launch_bounds__(256) void gemm_bt(const short* __restrict__ A,
                                               const short* __restrict__ BT,
                                               OutT* __restrict__ C,
                                               int M, int N, int K) {
    __shared__ short As[128 * 32];
    __shared__ short Bs[128 * 32];
    int tid  = threadIdx.x;
    int m0   = blockIdx.y * 128;
    int n0   = blockIdx.x * 128;
    int w    = tid >> 6, lane = tid & 63;
    int wm   = w >> 1,  wn   = w & 1;
    int quad = lane >> 4, l15 = lane & 15;
    int srow = lane >> 2;
    int scol = (lane & 3) * 8;

    float4v acc[4][4];
#pragma unroll
    for (int mi = 0; mi < 4; mi++)
#pragma unroll
        for (int ni = 0; ni < 4; ni++)
            acc[mi][ni] = {0.f, 0.f, 0.f, 0.f};

    for (int k0 = 0; k0 < K; k0 += 32) {
        __syncthreads();
#pragma unroll
        for (int t = 0; t < 2; t++) {
            int chunk = w * 2 + t;
            int r = chunk * 16 + srow;
            gload_lds16(&A[(m0 + r) * K + k0 + scol], &As[chunk * 16 * 32]);
            gload_lds16(&BT[(n0 + r) * K + k0 + scol], &Bs[chunk * 16 * 32]);
        }
        __syncthreads();
        short8 a[4], b[4];
#pragma unroll
        for (int mi = 0; mi < 4; mi++)
            a[mi] = *(const short8*)&As[(wm * 64 + mi * 16 + l15) * 32 + quad * 8];
#pragma unroll
        for (int ni = 0; ni < 4; ni++)
            b[ni] = *(const short8*)&Bs[(wn * 64 + ni * 16 + l15) * 32 + quad * 8];
#pragma unroll
        for (int mi = 0; mi < 4; mi++)
#pragma unroll
            for (int ni = 0; ni < 4; ni++)
                acc[mi][ni] = __builtin_amdgcn_mfma_f32_16x16x32_bf16(a[mi], b[ni], acc[mi][ni], 0, 0, 0);
    }

#pragma unroll
    for (int mi = 0; mi < 4; mi++)
#pragma unroll
        for (int ni = 0; ni < 4; ni++)
#pragma unroll
            for (int r = 0; r < 4; r++) {
                int row = m0 + wm * 64 + mi * 16 + quad * 4 + r;
                int col = n0 + wn * 64 + ni * 16 + l15;
                float v = acc[mi][ni][r];
                if constexpr (sizeof(OutT) == 2) C[row * N + col] = (OutT)f2bf(v);
                else                             C[row * N + col] = (OutT)v;
            }
}

// ------------- GEMM 64x128 tile (more blocks for small-N GEMM2) -------------
__global__ __launch_bounds__(256) void gemm_bt64(const short* __restrict__ A,
                                                 const short* __restrict__ BT,
                                                 float* __restrict__ C,
                                                 int M, int N, int K) {
    __shared__ short As[64 * 32];
    __shared__ short Bs[128 * 32];
    int tid  = threadIdx.x;
    int m0   = blockIdx.y * 64;
    int n0   = blockIdx.x * 128;
    int w    = tid >> 6, lane = tid & 63;
    int wm   = w >> 1,  wn   = w & 1;
    int quad = lane >> 4, l15 = lane & 15;
    int srow = lane >> 2;
    int scol = (lane & 3) * 8;

    float4v acc[2][4];
#pragma unroll
    for (int mi = 0; mi < 2; mi++)
#pragma unroll
        for (int ni = 0; ni < 4; ni++)
            acc[mi][ni] = {0.f, 0.f, 0.f, 0.f};

    for (int k0 = 0; k0 < K; k0 += 32) {
        __syncthreads();
        {
            int r = w * 16 + srow;
            gload_lds16(&A[(m0 + r) * K + k0 + scol], &As[w * 16 * 32]);
        }
#pragma unroll
        for (int t = 0; t < 2; t++) {
            int chunk = w * 2 + t;
            int r = chunk * 16 + srow;
            gload_lds16(&BT[(n0 + r) * K + k0 + scol], &Bs[chunk * 16 * 32]);
        }
        __syncthreads();
        short8 a[2], b[4];
#pragma unroll
        for (int mi = 0; mi < 2; mi++)
            a[mi] = *(const short8*)&As[(wm * 32 + mi * 16 + l15) * 32 + quad * 8];
#pragma unroll
        for (int ni = 0; ni < 4; ni++)
            b[ni] = *(const short8*)&Bs[(wn * 64 + ni * 16 + l15) * 32 + quad * 8];
#pragma unroll
        for (int mi = 0; mi < 2; mi++)
#pragma unroll
            for (int ni = 0; ni < 4; ni++)
                acc[mi][ni] = __builtin_amdgcn_mfma_f32_16x16x32_bf16(a[mi], b[ni], acc[mi][ni], 0, 0, 0);
    }

#pragma unroll
    for (int mi = 0; mi < 2; mi++)
#pragma unroll
        for (int ni = 0; ni < 4; ni++)
#pragma unroll
            for (int r = 0; r < 4; r++) {
                int row = m0 + wm * 32 + mi * 16 + quad * 4 + r;
                int col = n0 + wn * 64 + ni * 16 + l15;
                C[row * N + col] = acc[mi][ni][r];
            }
}

// ------------- flash attention, causal, bf16 MFMA, in-block s-split -------------
// 512 thr = 8 waves = 4 q-waves (32 rows each) x 2 s-splits. Block covers 128 q rows.
// Fixed-max softmax (Q pre-scaled by 0.125*log2e) -> split partials are additive:
// combine O and l through LDS at the end (2 barriers/block). Grid 32x16 = 2 blocks/CU,
// 16 waves/CU. Per-row K/V fetch amortization identical to the round-2 winner.
__global__ __launch_bounds__(512, 4) void attn_kernel(const short* __restrict__ qkv,
                                                      const short* __restrict__ vtp,
                                                      short* __restrict__ aout) {
    __shared__ short P[8][32 * 72];      // per-wave P tile (36.9 KB)
    __shared__ float Oc[4][32][66];      // split-1 O partials (33.8 KB)
    __shared__ float Lc[4][32];          // split-1 l partials
    int x = blockIdx.x;                  // 0..31
    int h = blockIdx.y;                  // 0..15
    // co-resident blocks (x,h),(x,h+8): q-weights t and 31-t sum constant
    int t = (h < 8) ? (31 - x) : x;
    int q0 = t * 128;
    int tid = threadIdx.x;
    int w = tid >> 6, lane = tid & 63;
    int qi = w >> 1, si = w & 1;         // q-wave 0..3, split 0..1
    int quad = lane >> 4, l15 = lane & 15;
    int qw = q0 + qi * 32;

    const short* Kbase = qkv + DM + h * HD;
    const short* Vbase = vtp + (h * HD) * SEQ;

    // Q fragments (A-layout: m=l15, k=quad*8+j); Q pre-scaled by 0.125*log2e
    short8 aq[2][2];
#pragma unroll
    for (int mi = 0; mi < 2; mi++)
#pragma unroll
        for (int kk = 0; kk < 2; kk++)
            aq[mi][kk] = *(const short8*)&qkv[(qw + mi * 16 + l15) * (3 * DM) + h * HD + kk * 32 + quad * 8];

    float lp[2][4];
    float4v o[2][4];
#pragma unroll
    for (int mi = 0; mi < 2; mi++)
#pragma unroll
        for (int r = 0; r < 4; r++)
            lp[mi][r] = 0.f;
#pragma unroll
    for (int mi = 0; mi < 2; mi++)
#pragma unroll
        for (int dt = 0; dt < 4; dt++)
            o[mi][dt] = {0.f, 0.f, 0.f, 0.f};

    short* Pw = P[w];
    int nT = qw / 64 + 1;      // tiles covering cols 0..qw+31
    int n0 = nT >> 1;
    int tbeg = si ? n0 : 0;
    int tend = si ? nT : n0;

    if (tbeg < tend) {
        short8 kc[8], vc[8];
        int sb = tbeg * 64;
#pragma unroll
        for (int ni = 0; ni < 4; ni++)
#pragma unroll
            for (int kk = 0; kk < 2; kk++)
                kc[ni * 2 + kk] = *(const short8*)&Kbase[(sb + ni * 16 + l15) * (3 * DM) + kk * 32 + quad * 8];
#pragma unroll
        for (int dt = 0; dt < 4; dt++)
#pragma unroll
            for (int kk = 0; kk < 2; kk++)
                vc[dt * 2 + kk] = *(const short8*)&Vbase[(dt * 16 + l15) * SEQ + sb + kk * 32 + quad * 8];

        for (int tt = tbeg; tt < tend; tt++) {
            int s0 = tt * 64;
            int sn = (tt + 1 < tend) ? s0 + 64 : s0;

            // S = Q K^T
            float4v s[2][4];
#pragma unroll
            for (int mi = 0; mi < 2; mi++)
#pragma unroll
                for (int ni = 0; ni < 4; ni++) {
                    float4v a = {0.f, 0.f, 0.f, 0.f};
#pragma unroll
                    for (int kk = 0; kk < 2; kk++)
                        a = __builtin_amdgcn_mfma_f32_16x16x32_bf16(aq[mi][kk], kc[ni * 2 + kk], a, 0, 0, 0);
                    s[mi][ni] = a;
                }
            // prefetch K(t+1)
#pragma unroll
            for (int ni = 0; ni < 4; ni++)
#pragma unroll
                for (int kk = 0; kk < 2; kk++)
                    kc[ni * 2 + kk] = *(const short8*)&Kbase[(sn + ni * 16 + l15) * (3 * DM) + kk * 32 + quad * 8];

            // causal mask (diagonal tile only; wave-uniform branch)
            if (s0 + 63 > qw) {
#pragma unroll
                for (int mi = 0; mi < 2; mi++)
#pragma unroll
                    for (int ni = 0; ni < 4; ni++)
#pragma unroll
                        for (int r = 0; r < 4; r++) {
                            int col = s0 + ni * 16 + l15;
                            int row = qw + mi * 16 + quad * 4 + r;
                            if (col > row) s[mi][ni][r] = -__builtin_inff();
                        }
            }
            // P = exp2(S); per-lane row partials; P -> LDS (C-layout)
#pragma unroll
            for (int mi = 0; mi < 2; mi++)
#pragma unroll
                for (int ni = 0; ni < 4; ni++)
#pragma unroll
                    for (int r = 0; r < 4; r++) {
                        float p = exp2f(s[mi][ni][r]);
                        lp[mi][r] += p;
                        Pw[(mi * 16 + quad * 4 + r) * 72 + ni * 16 + l15] = f2bf_fast(p);
                    }
            // O += P V
#pragma unroll
            for (int mi = 0; mi < 2; mi++) {
                short8 pa[2];
#pragma unroll
                for (int kk = 0; kk < 2; kk++)
                    pa[kk] = *(const short8*)&Pw[(mi * 16 + l15) * 72 + kk * 32 + quad * 8];
#pragma unroll
                for (int dt = 0; dt < 4; dt++)
#pragma unroll
                    for (int kk = 0; kk < 2; kk++)
                        o[mi][dt] = __builtin_amdgcn_mfma_f32_16x16x32_bf16(pa[kk], vc[dt * 2 + kk], o[mi][dt], 0, 0, 0);
            }
            // prefetch V(t+1)
#pragma unroll
            for (int dt = 0; dt < 4; dt++)
#pragma unroll
                for (int kk = 0; kk < 2; kk++)
                    vc[dt * 2 + kk] = *(const short8*)&Vbase[(dt * 16 + l15) * SEQ + sn + kk * 32 + quad * 8];
        }
    }

    // reduce l across 16 column-lanes (full row sums for this split's range)
#pragma unroll
    for (int mi = 0; mi < 2; mi++)
#pragma unroll
        for (int r = 0; r < 4; r++)
#pragma unroll
            for (int off = 1; off < 16; off <<= 1)
                lp[mi][r] += __shfl_xor(lp[mi][r], off, 64);

    // combine splits through LDS (fixed-max softmax -> partials additive)
    __syncthreads();
    if (si == 1) {
#pragma unroll
        for (int mi = 0; mi < 2; mi++)
#pragma unroll
            for (int r = 0; r < 4; r++) {
                int row = mi * 16 + quad * 4 + r;
#pragma unroll
                for (int dt = 0; dt < 4; dt++)
                    Oc[qi][row][dt * 16 + l15] = o[mi][dt][r];
                Lc[qi][row] = lp[mi][r];   // same value in all 16 l15 lanes
            }
    }
    __syncthreads();
    if (si == 0) {
#pragma unroll
        for (int mi = 0; mi < 2; mi++)
#pragma unroll
            for (int r = 0; r < 4; r++) {
                int row = mi * 16 + quad * 4 + r;
                float lt = lp[mi][r] + Lc[qi][row];
                float inv = 1.0f / lt;
#pragma unroll
                for (int dt = 0; dt < 4; dt++) {
                    float v = (o[mi][dt][r] + Oc[qi][row][dt * 16 + l15]) * inv;
                    aout[(qw + mi * 16 + quad * 4 + r) * DM + h * HD + dt * 16 + l15] = f2bf(v);
                }
            }
    }
}

extern "C" void kernel_launch(void* const* d_in, const int* in_sizes, int n_in,
                              void* d_out, int out_size, void* d_ws, size_t ws_size,
                              hipStream_t stream) {
    const float* x    = (const float*)d_in[0];
    const float* Wqkv = (const float*)d_in[1];
    const float* Wout = (const float*)d_in[2];
    float* out = (float*)d_out;

    char* ws = (char*)d_ws;
    short* xb    = (short*)(ws);                                 // 4096x1024 bf16   (8 MB)
    short* wqkvT = (short*)(ws + 8388608);                       // 3072x1024 bf16   (6 MB)
    short* woutT = (short*)(ws + 8388608 + 6291456);             // 1024x1024 bf16   (2 MB)
    short* qkv   = (short*)(ws + 16777216);                      // 4096x3072 bf16   (24 MB)
    short* vt    = (short*)(ws + 16777216 + 25165824);           // 16x64x4096 bf16  (8 MB)
    short* ao    = (short*)(ws + 16777216 + 25165824 + 8388608); // 4096x1024 bf16   (8 MB)

    const float SC = 0.18033688011112042f;  // (1/sqrt(64)) * log2(e)

    cast_x<<<4096, 256, 0, stream>>>(x, xb, (SEQ * DM) / 4);
    transpose_cast<<<dim3(3 * DM / 32, DM / 32), dim3(32, 8), 0, stream>>>(Wqkv, wqkvT, DM, 3 * DM, DM, SC);
    transpose_cast<<<dim3(DM / 32, DM / 32), dim3(32, 8), 0, stream>>>(Wout, woutT, DM, DM, 0, 1.0f);

    gemm_bt<short><<<dim3(3 * DM / 128, SEQ / 128), 256, 0, stream>>>(xb, wqkvT, qkv, SEQ, 3 * DM, DM);

    transpose_v<<<dim3(SEQ / 64, 1, NH), dim3(32, 8), 0, stream>>>(qkv, vt);

    attn_kernel<<<dim3(SEQ / 128, NH), 512, 0, stream>>>(qkv, vt, ao);

    gemm_bt64<<<dim3(DM / 128, SEQ / 64), 256, 0, stream>>>(ao, woutT, out, SEQ, DM, DM);
}

// Round 5
// 350.997 us; speedup vs baseline: 1.5605x; 1.5605x over previous
//
#include <hip/hip_runtime.h>

#define SEQ 4096
#define DM 1024
#define NH 16
#define HD 64

typedef __attribute__((ext_vector_type(8))) short short8;
typedef __attribute__((ext_vector_type(4))) short short4v;
typedef __attribute__((ext_vector_type(2))) short short2v;
typedef __attribute__((ext_vector_type(4))) float float4v;

__device__ __forceinline__ short f2bf(float f) {
    union { float f; unsigned u; } v; v.f = f;
    unsigned u = v.u;
    return (short)((u + 0x7fffu + ((u >> 16) & 1u)) >> 16);
}
// round-half-up bf16 (cheaper); used for P where tiny bias is irrelevant
__device__ __forceinline__ short f2bf_fast(float f) {
    union { float f; unsigned u; } v; v.f = f;
    return (short)((v.u + 0x8000u) >> 16);
}

__device__ __forceinline__ void gload_lds16(const void* g, void* l) {
    __builtin_amdgcn_global_load_lds(
        (const __attribute__((address_space(1))) void*)g,
        (__attribute__((address_space(3))) void*)l, 16, 0, 0);
}

// ---------------- cast x (fp32 -> bf16), vectorized ----------------
__global__ void cast_x(const float* __restrict__ in, short* __restrict__ out, int n4) {
    int i = blockIdx.x * blockDim.x + threadIdx.x;
    if (i < n4) {
        float4v x = ((const float4v*)in)[i];
        short4v o;
        o[0] = f2bf(x[0]); o[1] = f2bf(x[1]); o[2] = f2bf(x[2]); o[3] = f2bf(x[3]);
        ((short4v*)out)[i] = o;
    }
}

// ------ transpose + cast: fp32 [H][W] -> bf16 [W][H]; rows < scaled_rows get *scale ------
__global__ void transpose_cast(const float* __restrict__ in, short* __restrict__ out,
                               int H, int W, int scaled_rows, float scale) {
    __shared__ float tile[32][33];
    int bx = blockIdx.x * 32, by = blockIdx.y * 32;
    int tx = threadIdx.x, ty = threadIdx.y;   // 32 x 8
#pragma unroll
    for (int i = 0; i < 32; i += 8)
        tile[ty + i][tx] = in[(by + ty + i) * W + bx + tx];
    __syncthreads();
#pragma unroll
    for (int i = 0; i < 32; i += 8) {
        int orow = bx + ty + i;
        float sc = (orow < scaled_rows) ? scale : 1.0f;
        out[orow * H + by + tx] = f2bf(tile[tx][ty + i] * sc);
    }
}

// ------- V transpose: qkv bf16 [l][2048+h*64+d] -> vt [h][d][l], 64x64 short2 tiles -------
__global__ void transpose_v(const short* __restrict__ qkv, short* __restrict__ vt) {
    __shared__ short tile[64][66];
    int h = blockIdx.z;
    int l0 = blockIdx.x * 64;
    int tx = threadIdx.x, ty = threadIdx.y;   // 32 x 8
#pragma unroll
    for (int i = 0; i < 8; i++) {
        int r = ty + i * 8;
        short2v v = *(const short2v*)&qkv[(l0 + r) * (3 * DM) + 2 * DM + h * HD + 2 * tx];
        tile[r][2 * tx] = v[0];
        tile[r][2 * tx + 1] = v[1];
    }
    __syncthreads();
#pragma unroll
    for (int i = 0; i < 8; i++) {
        int d = ty + i * 8;
        short2v v;
        v[0] = tile[2 * tx][d];
        v[1] = tile[2 * tx + 1][d];
        *(short2v*)&vt[(h * HD + d) * SEQ + l0 + 2 * tx] = v;
    }
}

// ------------- GEMM: A[M,K] bf16 x BT[N,K] bf16 -> C[M,N], 128x128 tile -------------
template <typename OutT>
__global__ __launch_bounds__(256) void gemm_bt(const short* __restrict__ A,
                                               const short* __restrict__ BT,
                                               OutT* __restrict__ C,
                                               int M, int N, int K) {
    __shared__ short As[128 * 32];
    __shared__ short Bs[128 * 32];
    int tid  = threadIdx.x;
    int m0   = blockIdx.y * 128;
    int n0   = blockIdx.x * 128;
    int w    = tid >> 6, lane = tid & 63;
    int wm   = w >> 1,  wn   = w & 1;
    int quad = lane >> 4, l15 = lane & 15;
    int srow = lane >> 2;
    int scol = (lane & 3) * 8;

    float4v acc[4][4];
#pragma unroll
    for (int mi = 0; mi < 4; mi++)
#pragma unroll
        for (int ni = 0; ni < 4; ni++)
            acc[mi][ni] = {0.f, 0.f, 0.f, 0.f};

    for (int k0 = 0; k0 < K; k0 += 32) {
        __syncthreads();
#pragma unroll
        for (int t = 0; t < 2; t++) {
            int chunk = w * 2 + t;
            int r = chunk * 16 + srow;
            gload_lds16(&A[(m0 + r) * K + k0 + scol], &As[chunk * 16 * 32]);
            gload_lds16(&BT[(n0 + r) * K + k0 + scol], &Bs[chunk * 16 * 32]);
        }
        __syncthreads();
        short8 a[4], b[4];
#pragma unroll
        for (int mi = 0; mi < 4; mi++)
            a[mi] = *(const short8*)&As[(wm * 64 + mi * 16 + l15) * 32 + quad * 8];
#pragma unroll
        for (int ni = 0; ni < 4; ni++)
            b[ni] = *(const short8*)&Bs[(wn * 64 + ni * 16 + l15) * 32 + quad * 8];
#pragma unroll
        for (int mi = 0; mi < 4; mi++)
#pragma unroll
            for (int ni = 0; ni < 4; ni++)
                acc[mi][ni] = __builtin_amdgcn_mfma_f32_16x16x32_bf16(a[mi], b[ni], acc[mi][ni], 0, 0, 0);
    }

#pragma unroll
    for (int mi = 0; mi < 4; mi++)
#pragma unroll
        for (int ni = 0; ni < 4; ni++)
#pragma unroll
            for (int r = 0; r < 4; r++) {
                int row = m0 + wm * 64 + mi * 16 + quad * 4 + r;
                int col = n0 + wn * 64 + ni * 16 + l15;
                float v = acc[mi][ni][r];
                if constexpr (sizeof(OutT) == 2) C[row * N + col] = (OutT)f2bf(v);
                else                             C[row * N + col] = (OutT)v;
            }
}

// ------------- GEMM 64x128 tile (more blocks for small-N GEMM2) -------------
__global__ __launch_bounds__(256) void gemm_bt64(const short* __restrict__ A,
                                                 const short* __restrict__ BT,
                                                 float* __restrict__ C,
                                                 int M, int N, int K) {
    __shared__ short As[64 * 32];
    __shared__ short Bs[128 * 32];
    int tid  = threadIdx.x;
    int m0   = blockIdx.y * 64;
    int n0   = blockIdx.x * 128;
    int w    = tid >> 6, lane = tid & 63;
    int wm   = w >> 1,  wn   = w & 1;
    int quad = lane >> 4, l15 = lane & 15;
    int srow = lane >> 2;
    int scol = (lane & 3) * 8;

    float4v acc[2][4];
#pragma unroll
    for (int mi = 0; mi < 2; mi++)
#pragma unroll
        for (int ni = 0; ni < 4; ni++)
            acc[mi][ni] = {0.f, 0.f, 0.f, 0.f};

    for (int k0 = 0; k0 < K; k0 += 32) {
        __syncthreads();
        {
            int r = w * 16 + srow;
            gload_lds16(&A[(m0 + r) * K + k0 + scol], &As[w * 16 * 32]);
        }
#pragma unroll
        for (int t = 0; t < 2; t++) {
            int chunk = w * 2 + t;
            int r = chunk * 16 + srow;
            gload_lds16(&BT[(n0 + r) * K + k0 + scol], &Bs[chunk * 16 * 32]);
        }
        __syncthreads();
        short8 a[2], b[4];
#pragma unroll
        for (int mi = 0; mi < 2; mi++)
            a[mi] = *(const short8*)&As[(wm * 32 + mi * 16 + l15) * 32 + quad * 8];
#pragma unroll
        for (int ni = 0; ni < 4; ni++)
            b[ni] = *(const short8*)&Bs[(wn * 64 + ni * 16 + l15) * 32 + quad * 8];
#pragma unroll
        for (int mi = 0; mi < 2; mi++)
#pragma unroll
            for (int ni = 0; ni < 4; ni++)
                acc[mi][ni] = __builtin_amdgcn_mfma_f32_16x16x32_bf16(a[mi], b[ni], acc[mi][ni], 0, 0, 0);
    }

#pragma unroll
    for (int mi = 0; mi < 2; mi++)
#pragma unroll
        for (int ni = 0; ni < 4; ni++)
#pragma unroll
            for (int r = 0; r < 4; r++) {
                int row = m0 + wm * 32 + mi * 16 + quad * 4 + r;
                int col = n0 + wn * 64 + ni * 16 + l15;
                C[row * N + col] = acc[mi][ni][r];
            }
}

// ------------- flash attention, causal, bf16 MFMA, in-block s-split -------------
// 512 thr = 8 waves = 4 q-waves (32 rows each) x 2 s-splits. Block covers 128 q rows.
// Fixed-max softmax (Q pre-scaled by 0.125*log2e) -> split partials are additive:
// combine O and l through LDS at the end (2 barriers/block). Grid 32x16 = 2 blocks/CU,
// 16 waves/CU. Per-row K/V fetch amortization identical to the round-2 winner.
// NOTE: no min-waves arg in launch_bounds — (512,4) capped VGPR at 64 and spilled
// all K/V prefetch regs (R4: WRITE_SIZE 1 GB of scratch traffic, 405 us).
__global__ __launch_bounds__(512) void attn_kernel(const short* __restrict__ qkv,
                                                   const short* __restrict__ vtp,
                                                   short* __restrict__ aout) {
    __shared__ short P[8][32 * 72];      // per-wave P tile (36.9 KB)
    __shared__ float Oc[4][32][66];      // split-1 O partials (33.8 KB)
    __shared__ float Lc[4][32];          // split-1 l partials
    int x = blockIdx.x;                  // 0..31
    int h = blockIdx.y;                  // 0..15
    // co-resident blocks (x,h),(x,h+8): q-weights t and 31-t sum constant
    int t = (h < 8) ? (31 - x) : x;
    int q0 = t * 128;
    int tid = threadIdx.x;
    int w = tid >> 6, lane = tid & 63;
    int qi = w >> 1, si = w & 1;         // q-wave 0..3, split 0..1
    int quad = lane >> 4, l15 = lane & 15;
    int qw = q0 + qi * 32;

    const short* Kbase = qkv + DM + h * HD;
    const short* Vbase = vtp + (h * HD) * SEQ;

    // Q fragments (A-layout: m=l15, k=quad*8+j); Q pre-scaled by 0.125*log2e
    short8 aq[2][2];
#pragma unroll
    for (int mi = 0; mi < 2; mi++)
#pragma unroll
        for (int kk = 0; kk < 2; kk++)
            aq[mi][kk] = *(const short8*)&qkv[(qw + mi * 16 + l15) * (3 * DM) + h * HD + kk * 32 + quad * 8];

    float lp[2][4];
    float4v o[2][4];
#pragma unroll
    for (int mi = 0; mi < 2; mi++)
#pragma unroll
        for (int r = 0; r < 4; r++)
            lp[mi][r] = 0.f;
#pragma unroll
    for (int mi = 0; mi < 2; mi++)
#pragma unroll
        for (int dt = 0; dt < 4; dt++)
            o[mi][dt] = {0.f, 0.f, 0.f, 0.f};

    short* Pw = P[w];
    int nT = qw / 64 + 1;      // tiles covering cols 0..qw+31
    int n0 = nT >> 1;
    int tbeg = si ? n0 : 0;
    int tend = si ? nT : n0;

    if (tbeg < tend) {
        short8 kc[8], vc[8];
        int sb = tbeg * 64;
#pragma unroll
        for (int ni = 0; ni < 4; ni++)
#pragma unroll
            for (int kk = 0; kk < 2; kk++)
                kc[ni * 2 + kk] = *(const short8*)&Kbase[(sb + ni * 16 + l15) * (3 * DM) + kk * 32 + quad * 8];
#pragma unroll
        for (int dt = 0; dt < 4; dt++)
#pragma unroll
            for (int kk = 0; kk < 2; kk++)
                vc[dt * 2 + kk] = *(const short8*)&Vbase[(dt * 16 + l15) * SEQ + sb + kk * 32 + quad * 8];

        for (int tt = tbeg; tt < tend; tt++) {
            int s0 = tt * 64;
            int sn = (tt + 1 < tend) ? s0 + 64 : s0;

            // S = Q K^T
            float4v s[2][4];
#pragma unroll
            for (int mi = 0; mi < 2; mi++)
#pragma unroll
                for (int ni = 0; ni < 4; ni++) {
                    float4v a = {0.f, 0.f, 0.f, 0.f};
#pragma unroll
                    for (int kk = 0; kk < 2; kk++)
                        a = __builtin_amdgcn_mfma_f32_16x16x32_bf16(aq[mi][kk], kc[ni * 2 + kk], a, 0, 0, 0);
                    s[mi][ni] = a;
                }
            // prefetch K(t+1)
#pragma unroll
            for (int ni = 0; ni < 4; ni++)
#pragma unroll
                for (int kk = 0; kk < 2; kk++)
                    kc[ni * 2 + kk] = *(const short8*)&Kbase[(sn + ni * 16 + l15) * (3 * DM) + kk * 32 + quad * 8];

            // causal mask (diagonal tile only; wave-uniform branch)
            if (s0 + 63 > qw) {
#pragma unroll
                for (int mi = 0; mi < 2; mi++)
#pragma unroll
                    for (int ni = 0; ni < 4; ni++)
#pragma unroll
                        for (int r = 0; r < 4; r++) {
                            int col = s0 + ni * 16 + l15;
                            int row = qw + mi * 16 + quad * 4 + r;
                            if (col > row) s[mi][ni][r] = -__builtin_inff();
                        }
            }
            // P = exp2(S); per-lane row partials; P -> LDS (C-layout)
#pragma unroll
            for (int mi = 0; mi < 2; mi++)
#pragma unroll
                for (int ni = 0; ni < 4; ni++)
#pragma unroll
                    for (int r = 0; r < 4; r++) {
                        float p = exp2f(s[mi][ni][r]);
                        lp[mi][r] += p;
                        Pw[(mi * 16 + quad * 4 + r) * 72 + ni * 16 + l15] = f2bf_fast(p);
                    }
            // O += P V
#pragma unroll
            for (int mi = 0; mi < 2; mi++) {
                short8 pa[2];
#pragma unroll
                for (int kk = 0; kk < 2; kk++)
                    pa[kk] = *(const short8*)&Pw[(mi * 16 + l15) * 72 + kk * 32 + quad * 8];
#pragma unroll
                for (int dt = 0; dt < 4; dt++)
#pragma unroll
                    for (int kk = 0; kk < 2; kk++)
                        o[mi][dt] = __builtin_amdgcn_mfma_f32_16x16x32_bf16(pa[kk], vc[dt * 2 + kk], o[mi][dt], 0, 0, 0);
            }
            // prefetch V(t+1)
#pragma unroll
            for (int dt = 0; dt < 4; dt++)
#pragma unroll
                for (int kk = 0; kk < 2; kk++)
                    vc[dt * 2 + kk] = *(const short8*)&Vbase[(dt * 16 + l15) * SEQ + sn + kk * 32 + quad * 8];
        }
    }

    // reduce l across 16 column-lanes (full row sums for this split's range)
#pragma unroll
    for (int mi = 0; mi < 2; mi++)
#pragma unroll
        for (int r = 0; r < 4; r++)
#pragma unroll
            for (int off = 1; off < 16; off <<= 1)
                lp[mi][r] += __shfl_xor(lp[mi][r], off, 64);

    // combine splits through LDS (fixed-max softmax -> partials additive)
    __syncthreads();
    if (si == 1) {
#pragma unroll
        for (int mi = 0; mi < 2; mi++)
#pragma unroll
            for (int r = 0; r < 4; r++) {
                int row = mi * 16 + quad * 4 + r;
#pragma unroll
                for (int dt = 0; dt < 4; dt++)
                    Oc[qi][row][dt * 16 + l15] = o[mi][dt][r];
                Lc[qi][row] = lp[mi][r];   // same value in all 16 l15 lanes
            }
    }
    __syncthreads();
    if (si == 0) {
#pragma unroll
        for (int mi = 0; mi < 2; mi++)
#pragma unroll
            for (int r = 0; r < 4; r++) {
                int row = mi * 16 + quad * 4 + r;
                float lt = lp[mi][r] + Lc[qi][row];
                float inv = 1.0f / lt;
#pragma unroll
                for (int dt = 0; dt < 4; dt++) {
                    float v = (o[mi][dt][r] + Oc[qi][row][dt * 16 + l15]) * inv;
                    aout[(qw + mi * 16 + quad * 4 + r) * DM + h * HD + dt * 16 + l15] = f2bf(v);
                }
            }
    }
}

extern "C" void kernel_launch(void* const* d_in, const int* in_sizes, int n_in,
                              void* d_out, int out_size, void* d_ws, size_t ws_size,
                              hipStream_t stream) {
    const float* x    = (const float*)d_in[0];
    const float* Wqkv = (const float*)d_in[1];
    const float* Wout = (const float*)d_in[2];
    float* out = (float*)d_out;

    char* ws = (char*)d_ws;
    short* xb    = (short*)(ws);                                 // 4096x1024 bf16   (8 MB)
    short* wqkvT = (short*)(ws + 8388608);                       // 3072x1024 bf16   (6 MB)
    short* woutT = (short*)(ws + 8388608 + 6291456);             // 1024x1024 bf16   (2 MB)
    short* qkv   = (short*)(ws + 16777216);                      // 4096x3072 bf16   (24 MB)
    short* vt    = (short*)(ws + 16777216 + 25165824);           // 16x64x4096 bf16  (8 MB)
    short* ao    = (short*)(ws + 16777216 + 25165824 + 8388608); // 4096x1024 bf16   (8 MB)

    const float SC = 0.18033688011112042f;  // (1/sqrt(64)) * log2(e)

    cast_x<<<4096, 256, 0, stream>>>(x, xb, (SEQ * DM) / 4);
    transpose_cast<<<dim3(3 * DM / 32, DM / 32), dim3(32, 8), 0, stream>>>(Wqkv, wqkvT, DM, 3 * DM, DM, SC);
    transpose_cast<<<dim3(DM / 32, DM / 32), dim3(32, 8), 0, stream>>>(Wout, woutT, DM, DM, 0, 1.0f);

    gemm_bt<short><<<dim3(3 * DM / 128, SEQ / 128), 256, 0, stream>>>(xb, wqkvT, qkv, SEQ, 3 * DM, DM);

    transpose_v<<<dim3(SEQ / 64, 1, NH), dim3(32, 8), 0, stream>>>(qkv, vt);

    attn_kernel<<<dim3(SEQ / 128, NH), 512, 0, stream>>>(qkv, vt, ao);

    gemm_bt64<<<dim3(DM / 128, SEQ / 64), 256, 0, stream>>>(ao, woutT, out, SEQ, DM, DM);
}

// Round 6
// 265.008 us; speedup vs baseline: 2.0668x; 1.3245x over previous
//
#include <hip/hip_runtime.h>

#define SEQ 4096
#define DM 1024
#define NH 16
#define HD 64

typedef __attribute__((ext_vector_type(8))) short short8;
typedef __attribute__((ext_vector_type(4))) short short4v;
typedef __attribute__((ext_vector_type(2))) short short2v;
typedef __attribute__((ext_vector_type(4))) float float4v;

__device__ __forceinline__ short f2bf(float f) {
    union { float f; unsigned u; } v; v.f = f;
    unsigned u = v.u;
    return (short)((u + 0x7fffu + ((u >> 16) & 1u)) >> 16);
}
// round-half-up bf16 (cheaper); used for P where tiny bias is irrelevant
__device__ __forceinline__ short f2bf_fast(float f) {
    union { float f; unsigned u; } v; v.f = f;
    return (short)((v.u + 0x8000u) >> 16);
}

__device__ __forceinline__ void gload_lds16(const void* g, void* l) {
    __builtin_amdgcn_global_load_lds(
        (const __attribute__((address_space(1))) void*)g,
        (__attribute__((address_space(3))) void*)l, 16, 0, 0);
}

// ---------------- cast x (fp32 -> bf16), vectorized ----------------
__global__ void cast_x(const float* __restrict__ in, short* __restrict__ out, int n4) {
    int i = blockIdx.x * blockDim.x + threadIdx.x;
    if (i < n4) {
        float4v x = ((const float4v*)in)[i];
        short4v o;
        o[0] = f2bf(x[0]); o[1] = f2bf(x[1]); o[2] = f2bf(x[2]); o[3] = f2bf(x[3]);
        ((short4v*)out)[i] = o;
    }
}

// ------ transpose + cast: fp32 [H][W] -> bf16 [W][H]; rows < scaled_rows get *scale ------
__global__ void transpose_cast(const float* __restrict__ in, short* __restrict__ out,
                               int H, int W, int scaled_rows, float scale) {
    __shared__ float tile[32][33];
    int bx = blockIdx.x * 32, by = blockIdx.y * 32;
    int tx = threadIdx.x, ty = threadIdx.y;   // 32 x 8
#pragma unroll
    for (int i = 0; i < 32; i += 8)
        tile[ty + i][tx] = in[(by + ty + i) * W + bx + tx];
    __syncthreads();
#pragma unroll
    for (int i = 0; i < 32; i += 8) {
        int orow = bx + ty + i;
        float sc = (orow < scaled_rows) ? scale : 1.0f;
        out[orow * H + by + tx] = f2bf(tile[tx][ty + i] * sc);
    }
}

// ------- V transpose: qkv bf16 [l][2048+h*64+d] -> vt [h][d][l], 64x64 short2 tiles -------
__global__ void transpose_v(const short* __restrict__ qkv, short* __restrict__ vt) {
    __shared__ short tile[64][66];
    int h = blockIdx.z;
    int l0 = blockIdx.x * 64;
    int tx = threadIdx.x, ty = threadIdx.y;   // 32 x 8
#pragma unroll
    for (int i = 0; i < 8; i++) {
        int r = ty + i * 8;
        short2v v = *(const short2v*)&qkv[(l0 + r) * (3 * DM) + 2 * DM + h * HD + 2 * tx];
        tile[r][2 * tx] = v[0];
        tile[r][2 * tx + 1] = v[1];
    }
    __syncthreads();
#pragma unroll
    for (int i = 0; i < 8; i++) {
        int d = ty + i * 8;
        short2v v;
        v[0] = tile[2 * tx][d];
        v[1] = tile[2 * tx + 1][d];
        *(short2v*)&vt[(h * HD + d) * SEQ + l0 + 2 * tx] = v;
    }
}

// ------------- GEMM: A[M,K] bf16 x BT[N,K] bf16 -> C[M,N], 128x128 tile -------------
template <typename OutT>
__global__ __launch_bounds__(256) void gemm_bt(const short* __restrict__ A,
                                               const short* __restrict__ BT,
                                               OutT* __restrict__ C,
                                               int M, int N, int K) {
    __shared__ short As[128 * 32];
    __shared__ short Bs[128 * 32];
    int tid  = threadIdx.x;
    int m0   = blockIdx.y * 128;
    int n0   = blockIdx.x * 128;
    int w    = tid >> 6, lane = tid & 63;
    int wm   = w >> 1,  wn   = w & 1;
    int quad = lane >> 4, l15 = lane & 15;
    int srow = lane >> 2;
    int scol = (lane & 3) * 8;

    float4v acc[4][4];
#pragma unroll
    for (int mi = 0; mi < 4; mi++)
#pragma unroll
        for (int ni = 0; ni < 4; ni++)
            acc[mi][ni] = {0.f, 0.f, 0.f, 0.f};

    for (int k0 = 0; k0 < K; k0 += 32) {
        __syncthreads();
#pragma unroll
        for (int t = 0; t < 2; t++) {
            int chunk = w * 2 + t;
            int r = chunk * 16 + srow;
            gload_lds16(&A[(m0 + r) * K + k0 + scol], &As[chunk * 16 * 32]);
            gload_lds16(&BT[(n0 + r) * K + k0 + scol], &Bs[chunk * 16 * 32]);
        }
        __syncthreads();
        short8 a[4], b[4];
#pragma unroll
        for (int mi = 0; mi < 4; mi++)
            a[mi] = *(const short8*)&As[(wm * 64 + mi * 16 + l15) * 32 + quad * 8];
#pragma unroll
        for (int ni = 0; ni < 4; ni++)
            b[ni] = *(const short8*)&Bs[(wn * 64 + ni * 16 + l15) * 32 + quad * 8];
#pragma unroll
        for (int mi = 0; mi < 4; mi++)
#pragma unroll
            for (int ni = 0; ni < 4; ni++)
                acc[mi][ni] = __builtin_amdgcn_mfma_f32_16x16x32_bf16(a[mi], b[ni], acc[mi][ni], 0, 0, 0);
    }

#pragma unroll
    for (int mi = 0; mi < 4; mi++)
#pragma unroll
        for (int ni = 0; ni < 4; ni++)
#pragma unroll
            for (int r = 0; r < 4; r++) {
                int row = m0 + wm * 64 + mi * 16 + quad * 4 + r;
                int col = n0 + wn * 64 + ni * 16 + l15;
                float v = acc[mi][ni][r];
                if constexpr (sizeof(OutT) == 2) C[row * N + col] = (OutT)f2bf(v);
                else                             C[row * N + col] = (OutT)v;
            }
}

// ------------- GEMM 64x128 tile (more blocks for small-N GEMM2) -------------
__global__ __launch_bounds__(256) void gemm_bt64(const short* __restrict__ A,
                                                 const short* __restrict__ BT,
                                                 float* __restrict__ C,
                                                 int M, int N, int K) {
    __shared__ short As[64 * 32];
    __shared__ short Bs[128 * 32];
    int tid  = threadIdx.x;
    int m0   = blockIdx.y * 64;
    int n0   = blockIdx.x * 128;
    int w    = tid >> 6, lane = tid & 63;
    int wm   = w >> 1,  wn   = w & 1;
    int quad = lane >> 4, l15 = lane & 15;
    int srow = lane >> 2;
    int scol = (lane & 3) * 8;

    float4v acc[2][4];
#pragma unroll
    for (int mi = 0; mi < 2; mi++)
#pragma unroll
        for (int ni = 0; ni < 4; ni++)
            acc[mi][ni] = {0.f, 0.f, 0.f, 0.f};

    for (int k0 = 0; k0 < K; k0 += 32) {
        __syncthreads();
        {
            int r = w * 16 + srow;
            gload_lds16(&A[(m0 + r) * K + k0 + scol], &As[w * 16 * 32]);
        }
#pragma unroll
        for (int t = 0; t < 2; t++) {
            int chunk = w * 2 + t;
            int r = chunk * 16 + srow;
            gload_lds16(&BT[(n0 + r) * K + k0 + scol], &Bs[chunk * 16 * 32]);
        }
        __syncthreads();
        short8 a[2], b[4];
#pragma unroll
        for (int mi = 0; mi < 2; mi++)
            a[mi] = *(const short8*)&As[(wm * 32 + mi * 16 + l15) * 32 + quad * 8];
#pragma unroll
        for (int ni = 0; ni < 4; ni++)
            b[ni] = *(const short8*)&Bs[(wn * 64 + ni * 16 + l15) * 32 + quad * 8];
#pragma unroll
        for (int mi = 0; mi < 2; mi++)
#pragma unroll
            for (int ni = 0; ni < 4; ni++)
                acc[mi][ni] = __builtin_amdgcn_mfma_f32_16x16x32_bf16(a[mi], b[ni], acc[mi][ni], 0, 0, 0);
    }

#pragma unroll
    for (int mi = 0; mi < 2; mi++)
#pragma unroll
        for (int ni = 0; ni < 4; ni++)
#pragma unroll
            for (int r = 0; r < 4; r++) {
                int row = m0 + wm * 32 + mi * 16 + quad * 4 + r;
                int col = n0 + wn * 64 + ni * 16 + l15;
                C[row * N + col] = acc[mi][ni][r];
            }
}

// ------------- flash attention, causal, bf16 MFMA (R2 structure + XCD head pinning) -----
// 256 thr = 4 waves x 32 q-rows; block covers 128 q rows. Fixed-max softmax (Q pre-scaled
// by 0.125*log2e); K/V register-prefetched; no barriers in the main loop.
// Grid (h=16, y=32): linear id = y*16+h -> XCD = h%8, so each head's 32 blocks share one
// XCD whose 4MB L2 holds both resident heads' K+V (2x1MB) for the whole kernel.
// CU pairing is ids (c, c+256) = (y, y+16) same-h: t = y<16 ? 31-y : y-16 makes paired
// causal weights sum to 31 and dispatches heavy blocks first.
__global__ __launch_bounds__(256, 2) void attn_kernel(const short* __restrict__ qkv,
                                                      const short* __restrict__ vtp,
                                                      short* __restrict__ aout) {
    __shared__ short P[4][32 * 72];  // per-wave P tile, stride 72 shorts
    int h = blockIdx.x;              // 0..15  -> pins XCD = h%8
    int y = blockIdx.y;              // 0..31
    int t = (y < 16) ? (31 - y) : (y - 16);
    int q0 = t * 128;
    int tid = threadIdx.x;
    int w = tid >> 6, lane = tid & 63;
    int quad = lane >> 4, l15 = lane & 15;
    int qw = q0 + w * 32;

    const short* Kbase = qkv + DM + h * HD;       // + row*3072 + koff
    const short* Vbase = vtp + (h * HD) * SEQ;    // + (dt*16+l15)*SEQ + s + koff

    // Q fragments (A-layout: m=l15, k=quad*8+j); Q pre-scaled by 0.125*log2e
    short8 aq[2][2];
#pragma unroll
    for (int mi = 0; mi < 2; mi++)
#pragma unroll
        for (int kk = 0; kk < 2; kk++)
            aq[mi][kk] = *(const short8*)&qkv[(qw + mi * 16 + l15) * (3 * DM) + h * HD + kk * 32 + quad * 8];

    float lp[2][4];
    float4v o[2][4];
#pragma unroll
    for (int mi = 0; mi < 2; mi++)
#pragma unroll
        for (int r = 0; r < 4; r++)
            lp[mi][r] = 0.f;
#pragma unroll
    for (int mi = 0; mi < 2; mi++)
#pragma unroll
        for (int dt = 0; dt < 4; dt++)
            o[mi][dt] = {0.f, 0.f, 0.f, 0.f};

    short* Pw = P[w];
    int nT = qw / 64 + 1;

    short8 kc[8], vc[8];
#pragma unroll
    for (int ni = 0; ni < 4; ni++)
#pragma unroll
        for (int kk = 0; kk < 2; kk++)
            kc[ni * 2 + kk] = *(const short8*)&Kbase[(ni * 16 + l15) * (3 * DM) + kk * 32 + quad * 8];
#pragma unroll
    for (int dt = 0; dt < 4; dt++)
#pragma unroll
        for (int kk = 0; kk < 2; kk++)
            vc[dt * 2 + kk] = *(const short8*)&Vbase[(dt * 16 + l15) * SEQ + kk * 32 + quad * 8];

    for (int tt = 0; tt < nT; tt++) {
        int s0 = tt * 64;
        int sn = (tt + 1 < nT) ? s0 + 64 : s0;

        // S = Q K^T
        float4v s[2][4];
#pragma unroll
        for (int mi = 0; mi < 2; mi++)
#pragma unroll
            for (int ni = 0; ni < 4; ni++) {
                float4v a = {0.f, 0.f, 0.f, 0.f};
#pragma unroll
                for (int kk = 0; kk < 2; kk++)
                    a = __builtin_amdgcn_mfma_f32_16x16x32_bf16(aq[mi][kk], kc[ni * 2 + kk], a, 0, 0, 0);
                s[mi][ni] = a;
            }
        // prefetch K(t+1) (kc fully consumed above)
#pragma unroll
        for (int ni = 0; ni < 4; ni++)
#pragma unroll
            for (int kk = 0; kk < 2; kk++)
                kc[ni * 2 + kk] = *(const short8*)&Kbase[(sn + ni * 16 + l15) * (3 * DM) + kk * 32 + quad * 8];

        // causal mask only on diagonal tiles (wave-uniform branch)
        if (s0 + 63 > qw) {
#pragma unroll
            for (int mi = 0; mi < 2; mi++)
#pragma unroll
                for (int ni = 0; ni < 4; ni++)
#pragma unroll
                    for (int r = 0; r < 4; r++) {
                        int col = s0 + ni * 16 + l15;
                        int row = qw + mi * 16 + quad * 4 + r;
                        if (col > row) s[mi][ni][r] = -__builtin_inff();
                    }
        }
        // P = exp2(S); per-lane row partials of l; P -> LDS (C-layout)
#pragma unroll
        for (int mi = 0; mi < 2; mi++)
#pragma unroll
            for (int ni = 0; ni < 4; ni++)
#pragma unroll
                for (int r = 0; r < 4; r++) {
                    float p = exp2f(s[mi][ni][r]);
                    lp[mi][r] += p;
                    Pw[(mi * 16 + quad * 4 + r) * 72 + ni * 16 + l15] = f2bf_fast(p);
                }
        // O += P V
#pragma unroll
        for (int mi = 0; mi < 2; mi++) {
            short8 pa[2];
#pragma unroll
            for (int kk = 0; kk < 2; kk++)
                pa[kk] = *(const short8*)&Pw[(mi * 16 + l15) * 72 + kk * 32 + quad * 8];
#pragma unroll
            for (int dt = 0; dt < 4; dt++)
#pragma unroll
                for (int kk = 0; kk < 2; kk++)
                    o[mi][dt] = __builtin_amdgcn_mfma_f32_16x16x32_bf16(pa[kk], vc[dt * 2 + kk], o[mi][dt], 0, 0, 0);
        }
        // prefetch V(t+1) (vc fully consumed above)
#pragma unroll
        for (int dt = 0; dt < 4; dt++)
#pragma unroll
            for (int kk = 0; kk < 2; kk++)
                vc[dt * 2 + kk] = *(const short8*)&Vbase[(dt * 16 + l15) * SEQ + sn + kk * 32 + quad * 8];
    }

    // epilogue: reduce l across the 16 column-lanes (lands on rows quad*4+r), then O/l
#pragma unroll
    for (int mi = 0; mi < 2; mi++)
#pragma unroll
        for (int r = 0; r < 4; r++) {
#pragma unroll
            for (int off = 1; off < 16; off <<= 1)
                lp[mi][r] += __shfl_xor(lp[mi][r], off, 64);
        }
#pragma unroll
    for (int mi = 0; mi < 2; mi++)
#pragma unroll
        for (int r = 0; r < 4; r++) {
            float inv = 1.0f / lp[mi][r];
#pragma unroll
            for (int dt = 0; dt < 4; dt++) {
                float v = o[mi][dt][r] * inv;
                aout[(qw + mi * 16 + quad * 4 + r) * DM + h * HD + dt * 16 + l15] = f2bf(v);
            }
        }
}

extern "C" void kernel_launch(void* const* d_in, const int* in_sizes, int n_in,
                              void* d_out, int out_size, void* d_ws, size_t ws_size,
                              hipStream_t stream) {
    const float* x    = (const float*)d_in[0];
    const float* Wqkv = (const float*)d_in[1];
    const float* Wout = (const float*)d_in[2];
    float* out = (float*)d_out;

    char* ws = (char*)d_ws;
    short* xb    = (short*)(ws);                                 // 4096x1024 bf16   (8 MB)
    short* wqkvT = (short*)(ws + 8388608);                       // 3072x1024 bf16   (6 MB)
    short* woutT = (short*)(ws + 8388608 + 6291456);             // 1024x1024 bf16   (2 MB)
    short* qkv   = (short*)(ws + 16777216);                      // 4096x3072 bf16   (24 MB)
    short* vt    = (short*)(ws + 16777216 + 25165824);           // 16x64x4096 bf16  (8 MB)
    short* ao    = (short*)(ws + 16777216 + 25165824 + 8388608); // 4096x1024 bf16   (8 MB)

    const float SC = 0.18033688011112042f;  // (1/sqrt(64)) * log2(e)

    cast_x<<<4096, 256, 0, stream>>>(x, xb, (SEQ * DM) / 4);
    transpose_cast<<<dim3(3 * DM / 32, DM / 32), dim3(32, 8), 0, stream>>>(Wqkv, wqkvT, DM, 3 * DM, DM, SC);
    transpose_cast<<<dim3(DM / 32, DM / 32), dim3(32, 8), 0, stream>>>(Wout, woutT, DM, DM, 0, 1.0f);

    gemm_bt<short><<<dim3(3 * DM / 128, SEQ / 128), 256, 0, stream>>>(xb, wqkvT, qkv, SEQ, 3 * DM, DM);

    transpose_v<<<dim3(SEQ / 64, 1, NH), dim3(32, 8), 0, stream>>>(qkv, vt);

    attn_kernel<<<dim3(NH, SEQ / 128), 256, 0, stream>>>(qkv, vt, ao);

    gemm_bt64<<<dim3(DM / 128, SEQ / 64), 256, 0, stream>>>(ao, woutT, out, SEQ, DM, DM);
}

// Round 7
// 264.416 us; speedup vs baseline: 2.0714x; 1.0022x over previous
//
#include <hip/hip_runtime.h>

#define SEQ 4096
#define DM 1024
#define NH 16
#define HD 64

typedef __attribute__((ext_vector_type(8))) short short8;
typedef __attribute__((ext_vector_type(4))) short short4v;
typedef __attribute__((ext_vector_type(2))) short short2v;
typedef __attribute__((ext_vector_type(4))) float float4v;
typedef __attribute__((ext_vector_type(4))) int int4v;

__device__ __forceinline__ short f2bf(float f) {
    union { float f; unsigned u; } v; v.f = f;
    unsigned u = v.u;
    return (short)((u + 0x7fffu + ((u >> 16) & 1u)) >> 16);
}
// pack two fp32 -> dword of two round-half-up bf16 (3 VALU: add, add, perm)
__device__ __forceinline__ int pk2bf(float a, float b) {
    union { float f; unsigned u; } x, y; x.f = a; y.f = b;
    return (int)__builtin_amdgcn_perm(y.u + 0x8000u, x.u + 0x8000u, 0x07060302u);
}

__device__ __forceinline__ void gload_lds16(const void* g, void* l) {
    __builtin_amdgcn_global_load_lds(
        (const __attribute__((address_space(1))) void*)g,
        (__attribute__((address_space(3))) void*)l, 16, 0, 0);
}

// ---------------- cast x (fp32 -> bf16), vectorized ----------------
__global__ void cast_x(const float* __restrict__ in, short* __restrict__ out, int n4) {
    int i = blockIdx.x * blockDim.x + threadIdx.x;
    if (i < n4) {
        float4v x = ((const float4v*)in)[i];
        short4v o;
        o[0] = f2bf(x[0]); o[1] = f2bf(x[1]); o[2] = f2bf(x[2]); o[3] = f2bf(x[3]);
        ((short4v*)out)[i] = o;
    }
}

// ------ transpose + cast: fp32 [H][W] -> bf16 [W][H]; rows < scaled_rows get *scale ------
__global__ void transpose_cast(const float* __restrict__ in, short* __restrict__ out,
                               int H, int W, int scaled_rows, float scale) {
    __shared__ float tile[32][33];
    int bx = blockIdx.x * 32, by = blockIdx.y * 32;
    int tx = threadIdx.x, ty = threadIdx.y;   // 32 x 8
#pragma unroll
    for (int i = 0; i < 32; i += 8)
        tile[ty + i][tx] = in[(by + ty + i) * W + bx + tx];
    __syncthreads();
#pragma unroll
    for (int i = 0; i < 32; i += 8) {
        int orow = bx + ty + i;
        float sc = (orow < scaled_rows) ? scale : 1.0f;
        out[orow * H + by + tx] = f2bf(tile[tx][ty + i] * sc);
    }
}

// ------- V transpose: qkv bf16 [l][2048+h*64+d] -> vt [h][d][swz(l)] -------
// k-swizzle within each 32-col block so the attn PV B-fragment (k-permuted MFMA)
// reads plain short8 at quad*8: swz(s) = (s&~31)|((s&12)<<1)|((s&16)>>2)|(s&3).
__global__ void transpose_v(const short* __restrict__ qkv, short* __restrict__ vt) {
    __shared__ short tile[64][66];
    int h = blockIdx.z;
    int l0 = blockIdx.x * 64;
    int tx = threadIdx.x, ty = threadIdx.y;   // 32 x 8
#pragma unroll
    for (int i = 0; i < 8; i++) {
        int r = ty + i * 8;
        short2v v = *(const short2v*)&qkv[(l0 + r) * (3 * DM) + 2 * DM + h * HD + 2 * tx];
        tile[r][2 * tx] = v[0];
        tile[r][2 * tx + 1] = v[1];
    }
    __syncthreads();
#pragma unroll
    for (int i = 0; i < 8; i++) {
        int d = ty + i * 8;
        short2v v;
        v[0] = tile[2 * tx][d];
        v[1] = tile[2 * tx + 1][d];
        int s = l0 + 2 * tx;   // even -> swz keeps the pair contiguous
        int soff = (s & ~31) | ((s & 12) << 1) | ((s & 16) >> 2) | (s & 3);
        *(short2v*)&vt[(h * HD + d) * SEQ + soff] = v;
    }
}

// ------------- GEMM: A[M,K] bf16 x BT[N,K] bf16 -> C[M,N], 128x128 tile -------------
template <typename OutT>
__global__ __launch_bounds__(256) void gemm_bt(const short* __restrict__ A,
                                               const short* __restrict__ BT,
                                               OutT* __restrict__ C,
                                               int M, int N, int K) {
    __shared__ short As[128 * 32];
    __shared__ short Bs[128 * 32];
    int tid  = threadIdx.x;
    int m0   = blockIdx.y * 128;
    int n0   = blockIdx.x * 128;
    int w    = tid >> 6, lane = tid & 63;
    int wm   = w >> 1,  wn   = w & 1;
    int quad = lane >> 4, l15 = lane & 15;
    int srow = lane >> 2;
    int scol = (lane & 3) * 8;

    float4v acc[4][4];
#pragma unroll
    for (int mi = 0; mi < 4; mi++)
#pragma unroll
        for (int ni = 0; ni < 4; ni++)
            acc[mi][ni] = {0.f, 0.f, 0.f, 0.f};

    for (int k0 = 0; k0 < K; k0 += 32) {
        __syncthreads();
#pragma unroll
        for (int t = 0; t < 2; t++) {
            int chunk = w * 2 + t;
            int r = chunk * 16 + srow;
            gload_lds16(&A[(m0 + r) * K + k0 + scol], &As[chunk * 16 * 32]);
            gload_lds16(&BT[(n0 + r) * K + k0 + scol], &Bs[chunk * 16 * 32]);
        }
        __syncthreads();
        short8 a[4], b[4];
#pragma unroll
        for (int mi = 0; mi < 4; mi++)
            a[mi] = *(const short8*)&As[(wm * 64 + mi * 16 + l15) * 32 + quad * 8];
#pragma unroll
        for (int ni = 0; ni < 4; ni++)
            b[ni] = *(const short8*)&Bs[(wn * 64 + ni * 16 + l15) * 32 + quad * 8];
#pragma unroll
        for (int mi = 0; mi < 4; mi++)
#pragma unroll
            for (int ni = 0; ni < 4; ni++)
                acc[mi][ni] = __builtin_amdgcn_mfma_f32_16x16x32_bf16(a[mi], b[ni], acc[mi][ni], 0, 0, 0);
    }

#pragma unroll
    for (int mi = 0; mi < 4; mi++)
#pragma unroll
        for (int ni = 0; ni < 4; ni++)
#pragma unroll
            for (int r = 0; r < 4; r++) {
                int row = m0 + wm * 64 + mi * 16 + quad * 4 + r;
                int col = n0 + wn * 64 + ni * 16 + l15;
                float v = acc[mi][ni][r];
                if constexpr (sizeof(OutT) == 2) C[row * N + col] = (OutT)f2bf(v);
                else                             C[row * N + col] = (OutT)v;
            }
}

// ------------- GEMM 64x128 tile (more blocks for small-N GEMM2) -------------
__global__ __launch_bounds__(256) void gemm_bt64(const short* __restrict__ A,
                                                 const short* __restrict__ BT,
                                                 float* __restrict__ C,
                                                 int M, int N, int K) {
    __shared__ short As[64 * 32];
    __shared__ short Bs[128 * 32];
    int tid  = threadIdx.x;
    int m0   = blockIdx.y * 64;
    int n0   = blockIdx.x * 128;
    int w    = tid >> 6, lane = tid & 63;
    int wm   = w >> 1,  wn   = w & 1;
    int quad = lane >> 4, l15 = lane & 15;
    int srow = lane >> 2;
    int scol = (lane & 3) * 8;

    float4v acc[2][4];
#pragma unroll
    for (int mi = 0; mi < 2; mi++)
#pragma unroll
        for (int ni = 0; ni < 4; ni++)
            acc[mi][ni] = {0.f, 0.f, 0.f, 0.f};

    for (int k0 = 0; k0 < K; k0 += 32) {
        __syncthreads();
        {
            int r = w * 16 + srow;
            gload_lds16(&A[(m0 + r) * K + k0 + scol], &As[w * 16 * 32]);
        }
#pragma unroll
        for (int t = 0; t < 2; t++) {
            int chunk = w * 2 + t;
            int r = chunk * 16 + srow;
            gload_lds16(&BT[(n0 + r) * K + k0 + scol], &Bs[chunk * 16 * 32]);
        }
        __syncthreads();
        short8 a[2], b[4];
#pragma unroll
        for (int mi = 0; mi < 2; mi++)
            a[mi] = *(const short8*)&As[(wm * 32 + mi * 16 + l15) * 32 + quad * 8];
#pragma unroll
        for (int ni = 0; ni < 4; ni++)
            b[ni] = *(const short8*)&Bs[(wn * 64 + ni * 16 + l15) * 32 + quad * 8];
#pragma unroll
        for (int mi = 0; mi < 2; mi++)
#pragma unroll
            for (int ni = 0; ni < 4; ni++)
                acc[mi][ni] = __builtin_amdgcn_mfma_f32_16x16x32_bf16(a[mi], b[ni], acc[mi][ni], 0, 0, 0);
    }

#pragma unroll
    for (int mi = 0; mi < 2; mi++)
#pragma unroll
        for (int ni = 0; ni < 4; ni++)
#pragma unroll
            for (int r = 0; r < 4; r++) {
                int row = m0 + wm * 32 + mi * 16 + quad * 4 + r;
                int col = n0 + wn * 64 + ni * 16 + l15;
                C[row * N + col] = acc[mi][ni][r];
            }
}

// ------------- flash attention, causal, bf16 MFMA, register-only P -------------
// S^T trick: S-MFMA computes S^T = K.Q^T (operand swap, same regs) so each lane holds
// fixed q=l15 and 4 consecutive s (quad*4+r) -> P is A-fragment-shaped for PV after an
// in-register bf16 pack. PV uses a k-permuted 16x16x32 MFMA whose permutation is baked
// into vt's swizzled layout. No LDS, no libm exp2 (raw v_exp_f32). XCD head pinning
// (grid h-major) keeps each head's K/V in one XCD's L2 (R6: FETCH 135->12 MB).
__global__ __launch_bounds__(256, 2) void attn_kernel(const short* __restrict__ qkv,
                                                      const short* __restrict__ vtp,
                                                      short* __restrict__ aout) {
    int h = blockIdx.x;              // 0..15  -> pins XCD = h%8
    int y = blockIdx.y;              // 0..31
    int t = (y < 16) ? (31 - y) : (y - 16);  // CU pairs (y, y+16): weights sum to 31
    int q0 = t * 128;
    int tid = threadIdx.x;
    int w = tid >> 6, lane = tid & 63;
    int quad = lane >> 4, l15 = lane & 15;
    int qw = q0 + w * 32;

    const short* Kbase = qkv + DM + h * HD;
    const short* Vbase = vtp + (h * HD) * SEQ;

    // Q fragments (used as B-operand of the S^T MFMA); Q pre-scaled by 0.125*log2e
    short8 aq[2][2];
#pragma unroll
    for (int mi = 0; mi < 2; mi++)
#pragma unroll
        for (int kk = 0; kk < 2; kk++)
            aq[mi][kk] = *(const short8*)&qkv[(qw + mi * 16 + l15) * (3 * DM) + h * HD + kk * 32 + quad * 8];

    float lp[2] = {0.f, 0.f};        // per-lane row partial of l (lane owns q = qw+mi*16+l15)
    float4v o[2][4];
#pragma unroll
    for (int mi = 0; mi < 2; mi++)
#pragma unroll
        for (int dt = 0; dt < 4; dt++)
            o[mi][dt] = {0.f, 0.f, 0.f, 0.f};

    int nT = qw / 64 + 1;

    short8 kc[8], vc[8];
#pragma unroll
    for (int ni = 0; ni < 4; ni++)
#pragma unroll
        for (int kk = 0; kk < 2; kk++)
            kc[ni * 2 + kk] = *(const short8*)&Kbase[(ni * 16 + l15) * (3 * DM) + kk * 32 + quad * 8];
#pragma unroll
    for (int dt = 0; dt < 4; dt++)
#pragma unroll
        for (int pr = 0; pr < 2; pr++)
            vc[dt * 2 + pr] = *(const short8*)&Vbase[(dt * 16 + l15) * SEQ + pr * 32 + quad * 8];

    for (int tt = 0; tt < nT; tt++) {
        int s0 = tt * 64;
        int sn = (tt + 1 < nT) ? s0 + 64 : s0;

        // S^T = K Q^T : frag [mi][ni] holds S[q=qw+mi*16+l15][s=s0+ni*16+quad*4+r]
        float4v s[2][4];
#pragma unroll
        for (int mi = 0; mi < 2; mi++)
#pragma unroll
            for (int ni = 0; ni < 4; ni++) {
                float4v a = {0.f, 0.f, 0.f, 0.f};
#pragma unroll
                for (int kk = 0; kk < 2; kk++)
                    a = __builtin_amdgcn_mfma_f32_16x16x32_bf16(kc[ni * 2 + kk], aq[mi][kk], a, 0, 0, 0);
                s[mi][ni] = a;
            }
        // prefetch K(t+1) (kc fully consumed)
#pragma unroll
        for (int ni = 0; ni < 4; ni++)
#pragma unroll
            for (int kk = 0; kk < 2; kk++)
                kc[ni * 2 + kk] = *(const short8*)&Kbase[(sn + ni * 16 + l15) * (3 * DM) + kk * 32 + quad * 8];

        // P = exp2(S^T) (raw v_exp_f32), causal mask via select-0, l partial, bf16 pack
        bool diag = (s0 + 63 > qw);
        short8 pa[2][2];
#pragma unroll
        for (int mi = 0; mi < 2; mi++) {
            int qrow = qw + mi * 16 + l15;
#pragma unroll
            for (int ni = 0; ni < 4; ni++) {
#pragma unroll
                for (int r = 0; r < 4; r++) {
                    float p = __builtin_amdgcn_exp2f(s[mi][ni][r]);
                    if (diag) {
                        int scol = s0 + ni * 16 + quad * 4 + r;
                        p = (scol <= qrow) ? p : 0.f;
                    }
                    lp[mi] += p;
                    s[mi][ni][r] = p;
                }
            }
#pragma unroll
            for (int pr = 0; pr < 2; pr++) {
                int4v wpk;
                wpk[0] = pk2bf(s[mi][2 * pr][0], s[mi][2 * pr][1]);
                wpk[1] = pk2bf(s[mi][2 * pr][2], s[mi][2 * pr][3]);
                wpk[2] = pk2bf(s[mi][2 * pr + 1][0], s[mi][2 * pr + 1][1]);
                wpk[3] = pk2bf(s[mi][2 * pr + 1][2], s[mi][2 * pr + 1][3]);
                pa[mi][pr] = *(short8*)&wpk;
            }
        }
        // O += P V  (k-permuted MFMA; permutation baked into vt layout)
#pragma unroll
        for (int mi = 0; mi < 2; mi++)
#pragma unroll
            for (int dt = 0; dt < 4; dt++)
#pragma unroll
                for (int pr = 0; pr < 2; pr++)
                    o[mi][dt] = __builtin_amdgcn_mfma_f32_16x16x32_bf16(pa[mi][pr], vc[dt * 2 + pr], o[mi][dt], 0, 0, 0);
        // prefetch V(t+1) (vc fully consumed)
#pragma unroll
        for (int dt = 0; dt < 4; dt++)
#pragma unroll
            for (int pr = 0; pr < 2; pr++)
                vc[dt * 2 + pr] = *(const short8*)&Vbase[(dt * 16 + l15) * SEQ + sn + pr * 32 + quad * 8];
    }

    // epilogue: l[q=..+l15] = sum over quads; broadcast to C-layout rows; O/l
#pragma unroll
    for (int mi = 0; mi < 2; mi++) {
        lp[mi] += __shfl_xor(lp[mi], 16, 64);
        lp[mi] += __shfl_xor(lp[mi], 32, 64);
    }
#pragma unroll
    for (int mi = 0; mi < 2; mi++)
#pragma unroll
        for (int r = 0; r < 4; r++) {
            float lr = __shfl(lp[mi], quad * 4 + r, 16);   // l for row q = qw+mi*16+quad*4+r
            float inv = 1.0f / lr;
#pragma unroll
            for (int dt = 0; dt < 4; dt++) {
                float v = o[mi][dt][r] * inv;
                aout[(qw + mi * 16 + quad * 4 + r) * DM + h * HD + dt * 16 + l15] = f2bf(v);
            }
        }
}

extern "C" void kernel_launch(void* const* d_in, const int* in_sizes, int n_in,
                              void* d_out, int out_size, void* d_ws, size_t ws_size,
                              hipStream_t stream) {
    const float* x    = (const float*)d_in[0];
    const float* Wqkv = (const float*)d_in[1];
    const float* Wout = (const float*)d_in[2];
    float* out = (float*)d_out;

    char* ws = (char*)d_ws;
    short* xb    = (short*)(ws);                                 // 4096x1024 bf16   (8 MB)
    short* wqkvT = (short*)(ws + 8388608);                       // 3072x1024 bf16   (6 MB)
    short* woutT = (short*)(ws + 8388608 + 6291456);             // 1024x1024 bf16   (2 MB)
    short* qkv   = (short*)(ws + 16777216);                      // 4096x3072 bf16   (24 MB)
    short* vt    = (short*)(ws + 16777216 + 25165824);           // 16x64x4096 bf16  (8 MB)
    short* ao    = (short*)(ws + 16777216 + 25165824 + 8388608); // 4096x1024 bf16   (8 MB)

    const float SC = 0.18033688011112042f;  // (1/sqrt(64)) * log2(e)

    cast_x<<<4096, 256, 0, stream>>>(x, xb, (SEQ * DM) / 4);
    transpose_cast<<<dim3(3 * DM / 32, DM / 32), dim3(32, 8), 0, stream>>>(Wqkv, wqkvT, DM, 3 * DM, DM, SC);
    transpose_cast<<<dim3(DM / 32, DM / 32), dim3(32, 8), 0, stream>>>(Wout, woutT, DM, DM, 0, 1.0f);

    gemm_bt<short><<<dim3(3 * DM / 128, SEQ / 128), 256, 0, stream>>>(xb, wqkvT, qkv, SEQ, 3 * DM, DM);

    transpose_v<<<dim3(SEQ / 64, 1, NH), dim3(32, 8), 0, stream>>>(qkv, vt);

    attn_kernel<<<dim3(NH, SEQ / 128), 256, 0, stream>>>(qkv, vt, ao);

    gemm_bt64<<<dim3(DM / 128, SEQ / 64), 256, 0, stream>>>(ao, woutT, out, SEQ, DM, DM);
}

// Round 8
// 218.475 us; speedup vs baseline: 2.5070x; 1.2103x over previous
//
#include <hip/hip_runtime.h>

#define SEQ 4096
#define DM 1024
#define NH 16
#define HD 64

typedef __attribute__((ext_vector_type(8))) short short8;
typedef __attribute__((ext_vector_type(4))) short short4v;
typedef __attribute__((ext_vector_type(2))) short short2v;
typedef __attribute__((ext_vector_type(4))) float float4v;
typedef __attribute__((ext_vector_type(4))) int int4v;

__device__ __forceinline__ short f2bf(float f) {
    union { float f; unsigned u; } v; v.f = f;
    unsigned u = v.u;
    return (short)((u + 0x7fffu + ((u >> 16) & 1u)) >> 16);
}
// pack two fp32 -> dword of two round-half-up bf16 (3 VALU: add, add, perm)
__device__ __forceinline__ int pk2bf(float a, float b) {
    union { float f; unsigned u; } x, y; x.f = a; y.f = b;
    return (int)__builtin_amdgcn_perm(y.u + 0x8000u, x.u + 0x8000u, 0x07060302u);
}

__device__ __forceinline__ void gload_lds16(const void* g, void* l) {
    __builtin_amdgcn_global_load_lds(
        (const __attribute__((address_space(1))) void*)g,
        (__attribute__((address_space(3))) void*)l, 16, 0, 0);
}

// ---------------- cast x (fp32 -> bf16), vectorized ----------------
__global__ void cast_x(const float* __restrict__ in, short* __restrict__ out, int n4) {
    int i = blockIdx.x * blockDim.x + threadIdx.x;
    if (i < n4) {
        float4v x = ((const float4v*)in)[i];
        short4v o;
        o[0] = f2bf(x[0]); o[1] = f2bf(x[1]); o[2] = f2bf(x[2]); o[3] = f2bf(x[3]);
        ((short4v*)out)[i] = o;
    }
}

// ------ transpose + cast: fp32 [H][W] -> bf16 [W][H]; rows < scaled_rows get *scale ------
__global__ void transpose_cast(const float* __restrict__ in, short* __restrict__ out,
                               int H, int W, int scaled_rows, float scale) {
    __shared__ float tile[32][33];
    int bx = blockIdx.x * 32, by = blockIdx.y * 32;
    int tx = threadIdx.x, ty = threadIdx.y;   // 32 x 8
#pragma unroll
    for (int i = 0; i < 32; i += 8)
        tile[ty + i][tx] = in[(by + ty + i) * W + bx + tx];
    __syncthreads();
#pragma unroll
    for (int i = 0; i < 32; i += 8) {
        int orow = bx + ty + i;
        float sc = (orow < scaled_rows) ? scale : 1.0f;
        out[orow * H + by + tx] = f2bf(tile[tx][ty + i] * sc);
    }
}

// ------- V transpose: qkv bf16 [l][2048+h*64+d] -> vt [h][d][swz(l)] -------
// k-swizzle within each 32-col block so the attn PV B-fragment (k-permuted MFMA)
// reads plain short8 at quad*8: swz(s) = (s&~31)|((s&12)<<1)|((s&16)>>2)|(s&3).
__global__ void transpose_v(const short* __restrict__ qkv, short* __restrict__ vt) {
    __shared__ short tile[64][66];
    int h = blockIdx.z;
    int l0 = blockIdx.x * 64;
    int tx = threadIdx.x, ty = threadIdx.y;   // 32 x 8
#pragma unroll
    for (int i = 0; i < 8; i++) {
        int r = ty + i * 8;
        short2v v = *(const short2v*)&qkv[(l0 + r) * (3 * DM) + 2 * DM + h * HD + 2 * tx];
        tile[r][2 * tx] = v[0];
        tile[r][2 * tx + 1] = v[1];
    }
    __syncthreads();
#pragma unroll
    for (int i = 0; i < 8; i++) {
        int d = ty + i * 8;
        short2v v;
        v[0] = tile[2 * tx][d];
        v[1] = tile[2 * tx + 1][d];
        int s = l0 + 2 * tx;   // even -> swz keeps the pair contiguous
        int soff = (s & ~31) | ((s & 12) << 1) | ((s & 16) >> 2) | (s & 3);
        *(short2v*)&vt[(h * HD + d) * SEQ + soff] = v;
    }
}

// ------------- GEMM: A[M,K] bf16 x BT[N,K] bf16 -> C[M,N], 128x128 tile -------------
template <typename OutT>
__global__ __launch_bounds__(256) void gemm_bt(const short* __restrict__ A,
                                               const short* __restrict__ BT,
                                               OutT* __restrict__ C,
                                               int M, int N, int K) {
    __shared__ short As[128 * 32];
    __shared__ short Bs[128 * 32];
    int tid  = threadIdx.x;
    int m0   = blockIdx.y * 128;
    int n0   = blockIdx.x * 128;
    int w    = tid >> 6, lane = tid & 63;
    int wm   = w >> 1,  wn   = w & 1;
    int quad = lane >> 4, l15 = lane & 15;
    int srow = lane >> 2;
    int scol = (lane & 3) * 8;

    float4v acc[4][4];
#pragma unroll
    for (int mi = 0; mi < 4; mi++)
#pragma unroll
        for (int ni = 0; ni < 4; ni++)
            acc[mi][ni] = {0.f, 0.f, 0.f, 0.f};

    for (int k0 = 0; k0 < K; k0 += 32) {
        __syncthreads();
#pragma unroll
        for (int t = 0; t < 2; t++) {
            int chunk = w * 2 + t;
            int r = chunk * 16 + srow;
            gload_lds16(&A[(m0 + r) * K + k0 + scol], &As[chunk * 16 * 32]);
            gload_lds16(&BT[(n0 + r) * K + k0 + scol], &Bs[chunk * 16 * 32]);
        }
        __syncthreads();
        short8 a[4], b[4];
#pragma unroll
        for (int mi = 0; mi < 4; mi++)
            a[mi] = *(const short8*)&As[(wm * 64 + mi * 16 + l15) * 32 + quad * 8];
#pragma unroll
        for (int ni = 0; ni < 4; ni++)
            b[ni] = *(const short8*)&Bs[(wn * 64 + ni * 16 + l15) * 32 + quad * 8];
#pragma unroll
        for (int mi = 0; mi < 4; mi++)
#pragma unroll
            for (int ni = 0; ni < 4; ni++)
                acc[mi][ni] = __builtin_amdgcn_mfma_f32_16x16x32_bf16(a[mi], b[ni], acc[mi][ni], 0, 0, 0);
    }

#pragma unroll
    for (int mi = 0; mi < 4; mi++)
#pragma unroll
        for (int ni = 0; ni < 4; ni++)
#pragma unroll
            for (int r = 0; r < 4; r++) {
                int row = m0 + wm * 64 + mi * 16 + quad * 4 + r;
                int col = n0 + wn * 64 + ni * 16 + l15;
                float v = acc[mi][ni][r];
                if constexpr (sizeof(OutT) == 2) C[row * N + col] = (OutT)f2bf(v);
                else                             C[row * N + col] = (OutT)v;
            }
}

// ------------- GEMM 64x128 tile (more blocks for small-N GEMM2) -------------
__global__ __launch_bounds__(256) void gemm_bt64(const short* __restrict__ A,
                                                 const short* __restrict__ BT,
                                                 float* __restrict__ C,
                                                 int M, int N, int K) {
    __shared__ short As[64 * 32];
    __shared__ short Bs[128 * 32];
    int tid  = threadIdx.x;
    int m0   = blockIdx.y * 64;
    int n0   = blockIdx.x * 128;
    int w    = tid >> 6, lane = tid & 63;
    int wm   = w >> 1,  wn   = w & 1;
    int quad = lane >> 4, l15 = lane & 15;
    int srow = lane >> 2;
    int scol = (lane & 3) * 8;

    float4v acc[2][4];
#pragma unroll
    for (int mi = 0; mi < 2; mi++)
#pragma unroll
        for (int ni = 0; ni < 4; ni++)
            acc[mi][ni] = {0.f, 0.f, 0.f, 0.f};

    for (int k0 = 0; k0 < K; k0 += 32) {
        __syncthreads();
        {
            int r = w * 16 + srow;
            gload_lds16(&A[(m0 + r) * K + k0 + scol], &As[w * 16 * 32]);
        }
#pragma unroll
        for (int t = 0; t < 2; t++) {
            int chunk = w * 2 + t;
            int r = chunk * 16 + srow;
            gload_lds16(&BT[(n0 + r) * K + k0 + scol], &Bs[chunk * 16 * 32]);
        }
        __syncthreads();
        short8 a[2], b[4];
#pragma unroll
        for (int mi = 0; mi < 2; mi++)
            a[mi] = *(const short8*)&As[(wm * 32 + mi * 16 + l15) * 32 + quad * 8];
#pragma unroll
        for (int ni = 0; ni < 4; ni++)
            b[ni] = *(const short8*)&Bs[(wn * 64 + ni * 16 + l15) * 32 + quad * 8];
#pragma unroll
        for (int mi = 0; mi < 2; mi++)
#pragma unroll
            for (int ni = 0; ni < 4; ni++)
                acc[mi][ni] = __builtin_amdgcn_mfma_f32_16x16x32_bf16(a[mi], b[ni], acc[mi][ni], 0, 0, 0);
    }

#pragma unroll
    for (int mi = 0; mi < 2; mi++)
#pragma unroll
        for (int ni = 0; ni < 4; ni++)
#pragma unroll
            for (int r = 0; r < 4; r++) {
                int row = m0 + wm * 32 + mi * 16 + quad * 4 + r;
                int col = n0 + wn * 64 + ni * 16 + l15;
                C[row * N + col] = acc[mi][ni][r];
            }
}

// ------------- flash attention, causal, bf16 MFMA, LDS-staged K/V -------------
// R7 found the per-wave K/V fragment loads are 64-line gathers (lane stride 6/8 KB) --
// the TA pipe serializes ~64 line transactions per load, ~3k stall cyc/tile. Fix: all 4
// waves share each K/V tile, so stage it cooperatively: coalesced global loads (8 full
// lines/inst) -> VGPR -> ds_write_b128 into pad-72 LDS; fragments via ds_read_b128.
// Single buffer, 2 barriers/tile, next-tile loads issued right after staging writes
// (m97 pattern). Compute core unchanged: S^T register-P, raw v_exp_f32, k-permuted PV.
// All waves run block-uniform trip count (2t+2); causal select-0 masks the ragged edge.
__global__ __launch_bounds__(256) void attn_kernel(const short* __restrict__ qkv,
                                                   const short* __restrict__ vtp,
                                                   short* __restrict__ aout) {
    __shared__ short Ks[64 * 72];    // s-local row x d, pad 72 (9.2 KB)
    __shared__ short Vs[64 * 72];    // d-local row x swz(s), pad 72
    int h = blockIdx.x;              // 0..15  -> pins XCD = h%8
    int y = blockIdx.y;              // 0..31
    int t = (y < 16) ? (31 - y) : (y - 16);  // CU pairs (y, y+16): weights sum to 31
    int q0 = t * 128;
    int tid = threadIdx.x;
    int w = tid >> 6, lane = tid & 63;
    int quad = lane >> 4, l15 = lane & 15;
    int qw = q0 + w * 32;
    int r8 = lane >> 3, c8 = lane & 7;
    int srow = w * 16 + r8;          // this wave's staging rows: srow, srow+8

    const short* Kg = qkv + DM + h * HD;     // + row*3072 + c8*8
    const short* Vg = vtp + (h * HD) * SEQ;  // + d*4096 + s + c8*8

    // Q fragments (B-operand of the S^T MFMA); Q pre-scaled by 0.125*log2e
    short8 aq[2][2];
#pragma unroll
    for (int mi = 0; mi < 2; mi++)
#pragma unroll
        for (int kk = 0; kk < 2; kk++)
            aq[mi][kk] = *(const short8*)&qkv[(qw + mi * 16 + l15) * (3 * DM) + h * HD + kk * 32 + quad * 8];

    float lp[2] = {0.f, 0.f};
    float4v o[2][4];
#pragma unroll
    for (int mi = 0; mi < 2; mi++)
#pragma unroll
        for (int dt = 0; dt < 4; dt++)
            o[mi][dt] = {0.f, 0.f, 0.f, 0.f};

    int nTblk = 2 * t + 2;           // block-uniform tile count

    // preload tile 0 into staging regs
    short8 kg[2], vg[2];
#pragma unroll
    for (int i = 0; i < 2; i++) {
        kg[i] = *(const short8*)&Kg[(srow + 8 * i) * (3 * DM) + c8 * 8];
        vg[i] = *(const short8*)&Vg[(srow + 8 * i) * SEQ + c8 * 8];
    }

    for (int tt = 0; tt < nTblk; tt++) {
        int s0 = tt * 64;
        int sn = (tt + 1 < nTblk) ? s0 + 64 : s0;   // clamped

        __syncthreads();   // all waves done reading LDS from prev tile
#pragma unroll
        for (int i = 0; i < 2; i++) {
            *(short8*)&Ks[(srow + 8 * i) * 72 + c8 * 8] = kg[i];
            *(short8*)&Vs[(srow + 8 * i) * 72 + c8 * 8] = vg[i];
        }
        // issue next tile's coalesced global loads (hidden behind this tile's compute)
#pragma unroll
        for (int i = 0; i < 2; i++) {
            kg[i] = *(const short8*)&Kg[(sn + srow + 8 * i) * (3 * DM) + c8 * 8];
            vg[i] = *(const short8*)&Vg[(srow + 8 * i) * SEQ + sn + c8 * 8];
        }
        __syncthreads();   // LDS tile ready

        // fragments from LDS
        short8 kc[8], vc[8];
#pragma unroll
        for (int ni = 0; ni < 4; ni++)
#pragma unroll
            for (int kk = 0; kk < 2; kk++)
                kc[ni * 2 + kk] = *(const short8*)&Ks[(ni * 16 + l15) * 72 + kk * 32 + quad * 8];
#pragma unroll
        for (int dt = 0; dt < 4; dt++)
#pragma unroll
            for (int pr = 0; pr < 2; pr++)
                vc[dt * 2 + pr] = *(const short8*)&Vs[(dt * 16 + l15) * 72 + pr * 32 + quad * 8];

        // S^T = K Q^T : frag [mi][ni] holds S[q=qw+mi*16+l15][s=s0+ni*16+quad*4+r]
        float4v s[2][4];
#pragma unroll
        for (int mi = 0; mi < 2; mi++)
#pragma unroll
            for (int ni = 0; ni < 4; ni++) {
                float4v a = {0.f, 0.f, 0.f, 0.f};
#pragma unroll
                for (int kk = 0; kk < 2; kk++)
                    a = __builtin_amdgcn_mfma_f32_16x16x32_bf16(kc[ni * 2 + kk], aq[mi][kk], a, 0, 0, 0);
                s[mi][ni] = a;
            }

        // P = exp2(S^T) (raw v_exp_f32), causal mask via select-0, l partial, bf16 pack
        bool diag = (s0 + 63 > qw);
        short8 pa[2][2];
#pragma unroll
        for (int mi = 0; mi < 2; mi++) {
            int qrow = qw + mi * 16 + l15;
#pragma unroll
            for (int ni = 0; ni < 4; ni++) {
#pragma unroll
                for (int r = 0; r < 4; r++) {
                    float p = __builtin_amdgcn_exp2f(s[mi][ni][r]);
                    if (diag) {
                        int scol = s0 + ni * 16 + quad * 4 + r;
                        p = (scol <= qrow) ? p : 0.f;
                    }
                    lp[mi] += p;
                    s[mi][ni][r] = p;
                }
            }
#pragma unroll
            for (int pr = 0; pr < 2; pr++) {
                int4v wpk;
                wpk[0] = pk2bf(s[mi][2 * pr][0], s[mi][2 * pr][1]);
                wpk[1] = pk2bf(s[mi][2 * pr][2], s[mi][2 * pr][3]);
                wpk[2] = pk2bf(s[mi][2 * pr + 1][0], s[mi][2 * pr + 1][1]);
                wpk[3] = pk2bf(s[mi][2 * pr + 1][2], s[mi][2 * pr + 1][3]);
                pa[mi][pr] = *(short8*)&wpk;
            }
        }
        // O += P V  (k-permuted MFMA; permutation baked into vt layout)
#pragma unroll
        for (int mi = 0; mi < 2; mi++)
#pragma unroll
            for (int dt = 0; dt < 4; dt++)
#pragma unroll
                for (int pr = 0; pr < 2; pr++)
                    o[mi][dt] = __builtin_amdgcn_mfma_f32_16x16x32_bf16(pa[mi][pr], vc[dt * 2 + pr], o[mi][dt], 0, 0, 0);
    }

    // epilogue: l[q=..+l15] = sum over quads; broadcast to C-layout rows; O/l
#pragma unroll
    for (int mi = 0; mi < 2; mi++) {
        lp[mi] += __shfl_xor(lp[mi], 16, 64);
        lp[mi] += __shfl_xor(lp[mi], 32, 64);
    }
#pragma unroll
    for (int mi = 0; mi < 2; mi++)
#pragma unroll
        for (int r = 0; r < 4; r++) {
            float lr = __shfl(lp[mi], quad * 4 + r, 16);   // l for row q = qw+mi*16+quad*4+r
            float inv = 1.0f / lr;
#pragma unroll
            for (int dt = 0; dt < 4; dt++) {
                float v = o[mi][dt][r] * inv;
                aout[(qw + mi * 16 + quad * 4 + r) * DM + h * HD + dt * 16 + l15] = f2bf(v);
            }
        }
}

extern "C" void kernel_launch(void* const* d_in, const int* in_sizes, int n_in,
                              void* d_out, int out_size, void* d_ws, size_t ws_size,
                              hipStream_t stream) {
    const float* x    = (const float*)d_in[0];
    const float* Wqkv = (const float*)d_in[1];
    const float* Wout = (const float*)d_in[2];
    float* out = (float*)d_out;

    char* ws = (char*)d_ws;
    short* xb    = (short*)(ws);                                 // 4096x1024 bf16   (8 MB)
    short* wqkvT = (short*)(ws + 8388608);                       // 3072x1024 bf16   (6 MB)
    short* woutT = (short*)(ws + 8388608 + 6291456);             // 1024x1024 bf16   (2 MB)
    short* qkv   = (short*)(ws + 16777216);                      // 4096x3072 bf16   (24 MB)
    short* vt    = (short*)(ws + 16777216 + 25165824);           // 16x64x4096 bf16  (8 MB)
    short* ao    = (short*)(ws + 16777216 + 25165824 + 8388608); // 4096x1024 bf16   (8 MB)

    const float SC = 0.18033688011112042f;  // (1/sqrt(64)) * log2(e)

    cast_x<<<4096, 256, 0, stream>>>(x, xb, (SEQ * DM) / 4);
    transpose_cast<<<dim3(3 * DM / 32, DM / 32), dim3(32, 8), 0, stream>>>(Wqkv, wqkvT, DM, 3 * DM, DM, SC);
    transpose_cast<<<dim3(DM / 32, DM / 32), dim3(32, 8), 0, stream>>>(Wout, woutT, DM, DM, 0, 1.0f);

    gemm_bt<short><<<dim3(3 * DM / 128, SEQ / 128), 256, 0, stream>>>(xb, wqkvT, qkv, SEQ, 3 * DM, DM);

    transpose_v<<<dim3(SEQ / 64, 1, NH), dim3(32, 8), 0, stream>>>(qkv, vt);

    attn_kernel<<<dim3(NH, SEQ / 128), 256, 0, stream>>>(qkv, vt, ao);

    gemm_bt64<<<dim3(DM / 128, SEQ / 64), 256, 0, stream>>>(ao, woutT, out, SEQ, DM, DM);
}